// Round 1
// baseline (470.425 us; speedup 1.0000x reference)
//
#include <hip/hip_runtime.h>

// GCN 2-layer forward: x[N,3] @ W1[3,16] -> GCNConv -> relu -> @ W2[16,2] -> GCNConv -> log_softmax
// Trick: out[d] = dinv[d] * ( sum_{e: dst=d} h[src]*dinv[src] + h[d]*dinv[d] ) + b

__global__ void k_deg(const int* __restrict__ dst, int* __restrict__ degi, int E) {
    int e = blockIdx.x * blockDim.x + threadIdx.x;
    if (e < E) atomicAdd(&degi[dst[e]], 1);
}

// dinv = rsqrt(deg+1); h1 = x @ W1; g1 = h1 * dinv
__global__ void k_dense1(const float* __restrict__ x, const float* __restrict__ W1,
                         const int* __restrict__ degi, float* __restrict__ dinv,
                         float* __restrict__ g1, int N) {
    __shared__ float sW[48];   // W1 row-major [3][16]
    if (threadIdx.x < 48) sW[threadIdx.x] = W1[threadIdx.x];
    __syncthreads();
    int i = blockIdx.x * blockDim.x + threadIdx.x;
    if (i >= N) return;
    float di = rsqrtf((float)(degi[i] + 1));   // +1 self-loop
    dinv[i] = di;
    float x0 = x[3*i], x1 = x[3*i+1], x2 = x[3*i+2];
#pragma unroll
    for (int k = 0; k < 16; ++k) {
        float h = x0 * sW[k] + x1 * sW[16 + k] + x2 * sW[32 + k];
        g1[16*i + k] = h * di;
    }
}

// 16 threads per edge: lane k moves feature k
__global__ void k_scatter1(const int* __restrict__ src, const int* __restrict__ dst,
                           const float* __restrict__ g1, float* __restrict__ acc1,
                           long long total) {
    long long gid = (long long)blockIdx.x * blockDim.x + threadIdx.x;
    if (gid >= total) return;
    int e = (int)(gid >> 4);
    int k = (int)(gid & 15);
    int s = src[e], d = dst[e];
    atomicAdd(&acc1[16*d + k], g1[16*s + k]);
}

// out1 = (acc1 + g1)*dinv + b1 ; relu ; h2 = out1 @ W2 ; g2 = h2 * dinv
__global__ void k_node2(const float* __restrict__ acc1, const float* __restrict__ g1,
                        const float* __restrict__ dinv, const float* __restrict__ b1,
                        const float* __restrict__ W2, float* __restrict__ g2, int N) {
    __shared__ float sW[32];   // W2 row-major [16][2]
    __shared__ float sb[16];
    if (threadIdx.x < 32) sW[threadIdx.x] = W2[threadIdx.x];
    if (threadIdx.x < 16) sb[threadIdx.x] = b1[threadIdx.x];
    __syncthreads();
    int i = blockIdx.x * blockDim.x + threadIdx.x;
    if (i >= N) return;
    float di = dinv[i];
    float h0 = 0.f, h1 = 0.f;
    const float4* a4 = (const float4*)(acc1 + 16*(size_t)i);
    const float4* g4 = (const float4*)(g1 + 16*(size_t)i);
#pragma unroll
    for (int q = 0; q < 4; ++q) {
        float4 a = a4[q], g = g4[q];
        float r[4] = {a.x + g.x, a.y + g.y, a.z + g.z, a.w + g.w};
#pragma unroll
        for (int j = 0; j < 4; ++j) {
            int k = 4*q + j;
            float t = fmaxf(r[j]*di + sb[k], 0.f);
            h0 += t * sW[2*k];
            h1 += t * sW[2*k + 1];
        }
    }
    g2[2*i]     = h0 * di;
    g2[2*i + 1] = h1 * di;
}

// 2 threads per edge
__global__ void k_scatter2(const int* __restrict__ src, const int* __restrict__ dst,
                           const float* __restrict__ g2, float* __restrict__ acc2, int total) {
    int gid = blockIdx.x * blockDim.x + threadIdx.x;
    if (gid >= total) return;
    int e = gid >> 1, c = gid & 1;
    atomicAdd(&acc2[2*dst[e] + c], g2[2*src[e] + c]);
}

// o = (acc2 + g2)*dinv + b2 ; log_softmax over 2 classes
__global__ void k_final(const float* __restrict__ acc2, const float* __restrict__ g2,
                        const float* __restrict__ dinv, const float* __restrict__ b2,
                        float* __restrict__ out, int N) {
    int i = blockIdx.x * blockDim.x + threadIdx.x;
    if (i >= N) return;
    float di = dinv[i];
    float2 a = ((const float2*)acc2)[i];
    float2 g = ((const float2*)g2)[i];
    float o0 = (a.x + g.x) * di + b2[0];
    float o1 = (a.y + g.y) * di + b2[1];
    float m = fmaxf(o0, o1);
    float lse = m + logf(expf(o0 - m) + expf(o1 - m));
    ((float2*)out)[i] = make_float2(o0 - lse, o1 - lse);
}

extern "C" void kernel_launch(void* const* d_in, const int* in_sizes, int n_in,
                              void* d_out, int out_size, void* d_ws, size_t ws_size,
                              hipStream_t stream) {
    const float* x  = (const float*)d_in[0];
    const int*   ei = (const int*)d_in[1];   // [2, E] int
    const float* W1 = (const float*)d_in[2];
    const float* b1 = (const float*)d_in[3];
    const float* W2 = (const float*)d_in[4];
    const float* b2 = (const float*)d_in[5];
    float* out = (float*)d_out;

    const int N = in_sizes[0] / 3;
    const int E = in_sizes[1] / 2;
    const int* src = ei;
    const int* dst = ei + E;

    // ws layout (all 16B-aligned since N*4 = 400000 = 16*25000):
    // [degi N int][acc1 16N f][acc2 2N f][dinv N f][g1 16N f][g2 2N f]
    char* ws = (char*)d_ws;
    int*   degi = (int*)ws;
    float* acc1 = (float*)(ws + (size_t)N * 4);
    float* acc2 = acc1 + (size_t)16 * N;
    float* dinv = acc2 + (size_t)2 * N;
    float* g1   = dinv + N;
    float* g2   = g1 + (size_t)16 * N;

    // zero degi + acc1 + acc2 (contiguous)
    hipMemsetAsync(ws, 0, (size_t)N * 4 * (1 + 16 + 2), stream);

    int nb = (E + 255) / 256;
    k_deg<<<nb, 256, 0, stream>>>(dst, degi, E);

    nb = (N + 255) / 256;
    k_dense1<<<nb, 256, 0, stream>>>(x, W1, degi, dinv, g1, N);

    long long t1 = (long long)E * 16;
    nb = (int)((t1 + 255) / 256);
    k_scatter1<<<nb, 256, 0, stream>>>(src, dst, g1, acc1, t1);

    nb = (N + 255) / 256;
    k_node2<<<nb, 256, 0, stream>>>(acc1, g1, dinv, b1, W2, g2, N);

    int t2 = E * 2;
    nb = (t2 + 255) / 256;
    k_scatter2<<<nb, 256, 0, stream>>>(src, dst, g2, acc2, t2);

    nb = (N + 255) / 256;
    k_final<<<nb, 256, 0, stream>>>(acc2, g2, dinv, b2, out, N);
}